// Round 5
// baseline (264.727 us; speedup 1.0000x reference)
//
#include <hip/hip_runtime.h>
#include <hip/hip_bf16.h>
#include <stdint.h>

#define B_ 8
#define S_ 2048
#define DM 1024
#define DH 64
#define M_ (B_ * S_)  // 16384

typedef __attribute__((ext_vector_type(8))) short bf16x8;  // 8 bf16 = 4 VGPR
typedef __attribute__((ext_vector_type(4))) float f32x4;   // MFMA C/D frag

// fp32 -> bf16 round-to-nearest-even
__device__ __forceinline__ ushort f2bf(float x) {
    union { float f; uint32_t u; } v;
    v.f = x;
    uint32_t r = v.u + 0x7FFFu + ((v.u >> 16) & 1u);
    return (ushort)(r >> 16);
}

// ---------------------------------------------------------------------------
// W convert: 3 x [64][1024] fp32 -> bf16. 192 blocks x 256 thr x float4.
// ---------------------------------------------------------------------------
__global__ __launch_bounds__(256) void wconv_kernel(
    const float* __restrict__ W0, const float* __restrict__ W1,
    const float* __restrict__ W2, ushort* __restrict__ Wb) {
    int id = blockIdx.x * 256 + threadIdx.x;  // 0..49151
    int g = id >> 14;                         // 16384 float4 per W
    int off = (id & 16383) * 4;
    const float* W = (g == 0) ? W0 : (g == 1) ? W1 : W2;
    float4 w = *(const float4*)&W[off];
    ushort4 o;
    o.x = f2bf(w.x); o.y = f2bf(w.y); o.z = f2bf(w.z); o.w = f2bf(w.w);
    *(ushort4*)&Wb[g * 65536 + off] = o;
}

// ---------------------------------------------------------------------------
// Projection, LDS-free, head-split for occupancy: each wave owns 16 rows x
// 32 heads (half of DH). Waves 0/1 share rows r0..r0+15 (head halves 0/1),
// waves 2/3 share rows r0+16..r0+31. Duplicate X reads between paired waves
// are L1/L2 hits; HBM traffic unchanged. grid=(512,3) block=256 ->
// 1536 blocks = 6 blocks/CU = 24 waves/CU (VGPR <= 64 keeps the 8/SIMD cap).
// A-frag: lane reads X[(r0+lr)][kt + lg*8 .. +8] fp32 (32B) -> bf16 in reg.
// B-frag: lane reads Wb[head][kt + lg*8 .. +8] bf16 (16B, L2-hot).
// D-layout (HW-verified): col = lane&15, row = (lane>>4)*4 + reg.
// ---------------------------------------------------------------------------
__global__ __launch_bounds__(256) void proj_kernel(
    const float* __restrict__ X0, const float* __restrict__ X1,
    const float* __restrict__ X2, const ushort* __restrict__ Wb,
    ushort* __restrict__ Qp, ushort* __restrict__ Kp,
    ushort* __restrict__ Vt) {
    const int g = blockIdx.y;
    const float* X = (g == 0) ? X0 : (g == 1) ? X1 : X2;
    const ushort* W = Wb + g * (DH * DM);

    const int t = threadIdx.x;
    const int wid = t >> 6, lane = t & 63;
    const int lr = lane & 15, lg = lane >> 4;
    const int wr = wid >> 1;        // row half within block
    const int fh = wid & 1;         // head half (0: heads 0-31, 1: 32-63)
    const int r0 = blockIdx.x * 32 + wr * 16;
    const int h0 = fh * 32;

    const float* xp = X + (size_t)(r0 + lr) * DM + lg * 8;
    const ushort* wp = W + (size_t)(h0 + lr) * DM + lg * 8;

    f32x4 acc[2] = {};
#pragma unroll 2
    for (int kt = 0; kt < DM; kt += 32) {
        float4 x0 = *(const float4*)(xp + kt);
        float4 x1 = *(const float4*)(xp + kt + 4);
        bf16x8 a;
        a[0] = (short)f2bf(x0.x); a[1] = (short)f2bf(x0.y);
        a[2] = (short)f2bf(x0.z); a[3] = (short)f2bf(x0.w);
        a[4] = (short)f2bf(x1.x); a[5] = (short)f2bf(x1.y);
        a[6] = (short)f2bf(x1.z); a[7] = (short)f2bf(x1.w);
#pragma unroll
        for (int fj = 0; fj < 2; ++fj) {
            bf16x8 w = *(const bf16x8*)(wp + (size_t)fj * 16 * DM + kt);
            acc[fj] = __builtin_amdgcn_mfma_f32_16x16x32_bf16(a, w, acc[fj], 0, 0, 0);
        }
    }

    if (g < 2) {
        ushort* Y = (g == 0) ? Qp : Kp;
#pragma unroll
        for (int fj = 0; fj < 2; ++fj)
#pragma unroll
            for (int r = 0; r < 4; ++r)
                Y[(size_t)(r0 + lg * 4 + r) * DH + h0 + fj * 16 + lr] =
                    f2bf(acc[fj][r]);
    } else {
        // V transposed: Vt[b][dh][s]; 4 consecutive s per lane -> ushort4.
        const int bb = r0 >> 11;
        const int s0 = (r0 & 2047) + lg * 4;
#pragma unroll
        for (int fj = 0; fj < 2; ++fj) {
            ushort4 pk;
            pk.x = f2bf(acc[fj][0]); pk.y = f2bf(acc[fj][1]);
            pk.z = f2bf(acc[fj][2]); pk.w = f2bf(acc[fj][3]);
            *(ushort4*)&Vt[((size_t)bb * DH + h0 + fj * 16 + lr) * S_ + s0] = pk;
        }
    }
}

// ---------------------------------------------------------------------------
// Causal flash attention: 16-row q-tile per block, 4-way KV-split (1 wave per
// kv stripe, kt = wid, wid+4, ...), partial (m,l,O) merged through LDS.
// Swapped QK^T: s[cg] = mfma(K,Q) so lane (lr,lg) holds P[q=lr][kv=cg*16+lg*4+r]
// -> row softmax = in-lane reduce over 16 + shfl_xor(16,32).
// Block jt mapping pairs complements so each CU's resident blocks have equal
// total work. grid=(1024) block=256; all blocks co-resident (27KB LDS).
// ---------------------------------------------------------------------------
__global__ __launch_bounds__(256) void attn_kernel(
    const ushort* __restrict__ Qp, const ushort* __restrict__ Kp,
    const ushort* __restrict__ Vt, float* __restrict__ Out) {
    __shared__ ushort Pb[4][16][72];  // per-wave P (144B rows: 16B-aligned, bank-spread)
    __shared__ float Ol[4][16][68];   // per-wave partial O (272B rows)
    __shared__ float Ml[4][16], Ll[4][16];

    const int t = threadIdx.x;
    const int wid = t >> 6, lane = t & 63;
    const int lr = lane & 15, lg = lane >> 4;

    const int id = blockIdx.x;
    const int b = id & 7, jx = id >> 3;
    const int u = jx & 31, v = jx >> 5;
    const int jt = (v & 1) ? (127 - (2 * u + (v >> 1))) : (2 * u + (v >> 1));
    const int q0 = jt * 16;
    const int ktmax = q0 >> 6;
    const int nt = ktmax + 1;

    const ushort* Qb = Qp + (size_t)b * S_ * DH;
    const ushort* Kb = Kp + (size_t)b * S_ * DH;
    const ushort* Vb = Vt + (size_t)b * DH * S_;

    bf16x8 qf0 = *(const bf16x8*)&Qb[(size_t)(q0 + lr) * DH + lg * 8];
    bf16x8 qf1 = *(const bf16x8*)&Qb[(size_t)(q0 + lr) * DH + 32 + lg * 8];

    f32x4 o[4] = {};
    float m = -1e30f, l = 0.f;  // state for q-row lr
    const float scale = 0.125f;

    for (int kt = wid; kt < nt; kt += 4) {
        const int kv0 = kt * 64;

        // S^T = K @ Q^T
        f32x4 s[4];
#pragma unroll
        for (int cg = 0; cg < 4; ++cg) {
            const ushort* kr = &Kb[(size_t)(kv0 + cg * 16 + lr) * DH + lg * 8];
            bf16x8 k0 = *(const bf16x8*)kr;
            bf16x8 k1 = *(const bf16x8*)(kr + 32);
            f32x4 z = {};
            s[cg] = __builtin_amdgcn_mfma_f32_16x16x32_bf16(k0, qf0, z, 0, 0, 0);
            s[cg] = __builtin_amdgcn_mfma_f32_16x16x32_bf16(k1, qf1, s[cg], 0, 0, 0);
        }

        // scale + causal mask (kv = kv0 + cg*16 + lg*4 + r, q = q0 + lr)
        if (kt == ktmax) {
#pragma unroll
            for (int cg = 0; cg < 4; ++cg)
#pragma unroll
                for (int r = 0; r < 4; ++r) {
                    int kv = kv0 + cg * 16 + lg * 4 + r;
                    s[cg][r] = (kv <= q0 + lr) ? s[cg][r] * scale : -1e30f;
                }
        } else {
#pragma unroll
            for (int cg = 0; cg < 4; ++cg) s[cg] = s[cg] * scale;
        }

        // online softmax for q-row lr (16 vals in-lane + 4 lanes via xor 16/32)
        float mx = -1e30f;
#pragma unroll
        for (int cg = 0; cg < 4; ++cg)
            mx = fmaxf(mx, fmaxf(fmaxf(s[cg][0], s[cg][1]),
                                 fmaxf(s[cg][2], s[cg][3])));
        mx = fmaxf(mx, __shfl_xor(mx, 16));
        mx = fmaxf(mx, __shfl_xor(mx, 32));
        float mn = fmaxf(m, mx);
        float corr = __expf(m - mn);
        m = mn;
        float rs = 0.f;
#pragma unroll
        for (int cg = 0; cg < 4; ++cg)
#pragma unroll
            for (int r = 0; r < 4; ++r) {
                float e = __expf(s[cg][r] - mn);
                s[cg][r] = e;
                rs += e;
            }
        rs += __shfl_xor(rs, 16);
        rs += __shfl_xor(rs, 32);
        l = l * corr + rs;

        // rescale O: its row is lg*4+r; fetch that row's corr from lane lg*4+r
        float co[4];
#pragma unroll
        for (int r = 0; r < 4; ++r) co[r] = __shfl(corr, lg * 4 + r);
#pragma unroll
        for (int fj = 0; fj < 4; ++fj)
#pragma unroll
            for (int r = 0; r < 4; ++r) o[fj][r] *= co[r];

        // P -> LDS (4 x b64) -> A-frags
#pragma unroll
        for (int cg = 0; cg < 4; ++cg) {
            ushort4 pk;
            pk.x = f2bf(s[cg][0]); pk.y = f2bf(s[cg][1]);
            pk.z = f2bf(s[cg][2]); pk.w = f2bf(s[cg][3]);
            *(ushort4*)&Pb[wid][lr][cg * 16 + lg * 4] = pk;
        }
        asm volatile("s_waitcnt lgkmcnt(0)" ::: "memory");
        __builtin_amdgcn_sched_barrier(0);
        bf16x8 pa0 = *(bf16x8*)&Pb[wid][lr][lg * 8];
        bf16x8 pa1 = *(bf16x8*)&Pb[wid][lr][32 + lg * 8];
        asm volatile("" ::: "memory");

        // O += P @ V
#pragma unroll
        for (int fj = 0; fj < 4; ++fj) {
            const ushort* vr = &Vb[(size_t)(fj * 16 + lr) * S_ + kv0 + lg * 8];
            bf16x8 v0 = *(const bf16x8*)vr;
            bf16x8 v1 = *(const bf16x8*)(vr + 32);
            o[fj] = __builtin_amdgcn_mfma_f32_16x16x32_bf16(pa0, v0, o[fj], 0, 0, 0);
            o[fj] = __builtin_amdgcn_mfma_f32_16x16x32_bf16(pa1, v1, o[fj], 0, 0, 0);
        }
    }

    // write unnormalized partials
#pragma unroll
    for (int fj = 0; fj < 4; ++fj)
#pragma unroll
        for (int r = 0; r < 4; ++r)
            Ol[wid][lg * 4 + r][fj * 16 + lr] = o[fj][r];
    if (lg == 0) {
        Ml[wid][lr] = m;
        Ll[wid][lr] = l;
    }
    __syncthreads();

    // merge 4 partials; thread t handles row t>>4, cols (t&15)*4..+4
    {
        const int row = t >> 4, c0 = (t & 15) * 4;
        float M = fmaxf(fmaxf(Ml[0][row], Ml[1][row]),
                        fmaxf(Ml[2][row], Ml[3][row]));
        float denom = 0.f;
        float a0 = 0.f, a1 = 0.f, a2 = 0.f, a3 = 0.f;
#pragma unroll
        for (int w = 0; w < 4; ++w) {
            float sc = __expf(Ml[w][row] - M);
            denom += Ll[w][row] * sc;
            float4 ov = *(const float4*)&Ol[w][row][c0];
            a0 += ov.x * sc; a1 += ov.y * sc; a2 += ov.z * sc; a3 += ov.w * sc;
        }
        float inv = 1.f / denom;
        float4 res = make_float4(a0 * inv, a1 * inv, a2 * inv, a3 * inv);
        *(float4*)&Out[((size_t)b * S_ + q0 + row) * DH + c0] = res;
    }
}

extern "C" void kernel_launch(void* const* d_in, const int* in_sizes, int n_in,
                              void* d_out, int out_size, void* d_ws,
                              size_t ws_size, hipStream_t stream) {
    const float* q_in = (const float*)d_in[0];
    const float* k_in = (const float*)d_in[1];
    const float* v_in = (const float*)d_in[2];
    const float* wq = (const float*)d_in[3];
    const float* wk = (const float*)d_in[4];
    const float* wv = (const float*)d_in[5];
    float* out = (float*)d_out;

    ushort* w = (ushort*)d_ws;
    const size_t MD = (size_t)M_ * DH;  // 1048576
    ushort* Qp = w;
    ushort* Kp = w + MD;
    ushort* Vt = w + 2 * MD;
    ushort* Wb = w + 3 * MD;  // 3*64*1024 bf16

    wconv_kernel<<<192, 256, 0, stream>>>(wq, wk, wv, Wb);
    proj_kernel<<<dim3(512, 3), 256, 0, stream>>>(q_in, k_in, v_in, Wb, Qp, Kp,
                                                  Vt);
    attn_kernel<<<1024, 256, 0, stream>>>(Qp, Kp, Vt, out);
}